// Round 13
// baseline (864.963 us; speedup 1.0000x reference)
//
#include <hip/hip_runtime.h>
#include <cstdint>
#include <cstddef>

// FoldingBlock round 12: R11 base (835us) with bp's 4-phase K-tile merged to
// 2 phases (4 barriers/tile instead of 8). Staging/vmcnt cadence is an exact
// isomorphism of the R6/R11 schedule (race-free by the same region argument);
// MFMA K-order per accumulator unchanged -> bit-identical math.
// p1 = up(p); pdelta = p - down(p1); out = p1 + up(pdelta)

typedef unsigned short u16;
typedef __bf16 bf16x8 __attribute__((ext_vector_type(8)));
typedef float f32x4 __attribute__((ext_vector_type(4)));

__device__ __forceinline__ u16 f2bf(float f) {
    unsigned u = __builtin_bit_cast(unsigned, f);
    unsigned r = (u + 0x7fffu + ((u >> 16) & 1u)) >> 16;
    return (u16)r;
}
__device__ __forceinline__ float bf2f(u16 h) {
    unsigned u = ((unsigned)h) << 16;
    return __builtin_bit_cast(float, u);
}
__device__ __forceinline__ bf16x8 ldfrag(const u16* p) {
    return __builtin_bit_cast(bf16x8, *reinterpret_cast<const uint4*>(p));
}
__device__ __forceinline__ void gload16(const u16* g, u16* l) {
    __builtin_amdgcn_global_load_lds((__attribute__((address_space(1))) void*)g,
                                     (__attribute__((address_space(3))) void*)l,
                                     16, 0, 0);
}
__device__ __forceinline__ unsigned ldsaddr(const u16* p) {
    return (unsigned)(size_t)(const __attribute__((address_space(3))) u16*)p;
}
__device__ __forceinline__ bf16x8 dsr128(unsigned a) {
    f32x4 r;
    asm volatile("ds_read_b128 %0, %1" : "=v"(r) : "v"(a));
    return __builtin_bit_cast(bf16x8, r);
}

#define FENCE asm volatile("" ::: "memory")
#define BAR() do { FENCE; __builtin_amdgcn_s_barrier(); FENCE; } while (0)
#define VMC(N) asm volatile("s_waitcnt vmcnt(" #N ")" ::: "memory")
#define LGKM(N) do { asm volatile("s_waitcnt lgkmcnt(" #N ")" ::: "memory"); \
                     __builtin_amdgcn_sched_barrier(0); } while (0)

// XCD-chunked swizzle (8 XCDs); identity when nwg not divisible by 8.
__device__ __forceinline__ int xcd_swz(int lin, int nwg) {
    if ((nwg & 7) == 0) { const int q = nwg >> 3; lin = (lin & 7) * q + (lin >> 3); }
    return lin;
}

// ================= BIG kernel: BM=256, BN=256, BK=64, 2 phases/tile ========
// Modes: 1 HLG (A=cat(p,upout) K=1024 -> h,l,gT), 3 X, 4 F1.
template<int MODE>
__global__ __launch_bounds__(512, 1)
void bp(const u16* __restrict__ A0, const u16* __restrict__ A1,
        const u16* __restrict__ Bt, const float* __restrict__ bias,
        const float* __restrict__ EXf, const u16* __restrict__ EXb,
        u16* __restrict__ outB, u16* __restrict__ out1, u16* __restrict__ out2,
        int K, long sB)
{
    __shared__ __align__(16) u16 As[2][16384];
    __shared__ __align__(16) u16 Bs[2][16384];

    const int lin = xcd_swz(blockIdx.y * gridDim.x + blockIdx.x,
                            gridDim.x * gridDim.y);
    const int b    = lin / gridDim.x;
    const int gn0  = (lin % gridDim.x) * 256;
    const int tid  = threadIdx.x;
    const int lane = tid & 63;
    const int w    = tid >> 6;
    const int wr   = w >> 2, wc = w & 3;
    const int wrow0 = wr * 128, wcol0 = wc * 64;
    const int lm   = lane & 15, hk = lane >> 4;
    const int NT   = K / 64;

    const int srow = tid & 255;
    const int su   = tid >> 8;

    const u16* gA0;
    const u16* gA1 = nullptr;
    if constexpr (MODE == 1) {
        gA0 = A0 + ((size_t)b << 15) + (size_t)(srow & 63) * 512 + su * 8;
        gA1 = A1 + ((size_t)b << 17) + (size_t)srow * 512 + su * 8;
    } else if constexpr (MODE == 3) {
        gA0 = A0 + ((size_t)b << 16) + (size_t)srow * 256 + su * 8;
    } else { // 4
        gA0 = A0 + ((size_t)b << 18) + (size_t)srow * 1024 + su * 8;
    }
    const u16* gB0 = Bt + (size_t)b * sB + (size_t)(gn0 + srow) * K + su * 8;

    u16* dA = &As[0][(size_t)(su * 256 + srow) * 8];
    u16* dB = &Bs[0][(size_t)(su * 256 + srow) * 8];

    auto stgA = [&](int kt, int buf, int rp) {
        const u16* g;
        if constexpr (MODE == 1) g = (kt < 8) ? (gA0 + kt * 64) : (gA1 + (kt - 8) * 64);
        else                     g = gA0 + kt * 64;
        u16* d = dA + buf * 16384 + rp * 8192;
        gload16(g + rp * 32,      d);
        gload16(g + rp * 32 + 16, d + 4096);
    };
    auto stgB = [&](int kt, int buf, int rp) {
        const u16* g = gB0 + kt * 64 + rp * 32;
        u16* d = dB + buf * 16384 + rp * 8192;
        gload16(g,      d);
        gload16(g + 16, d + 4096);
    };

    const u16* rA = &As[0][(size_t)(hk * 256 + wrow0 + lm) * 8];
    const u16* rB = &Bs[0][(size_t)(hk * 256 + wcol0 + lm) * 8];

    f32x4 acc[8][4];
    #pragma unroll
    for (int i = 0; i < 8; ++i)
        #pragma unroll
        for (int j = 0; j < 4; ++j)
            acc[i][j] = (f32x4){0.f, 0.f, 0.f, 0.f};

    // prologue: tile0 fully (8 loads), tile1 rp0 halves (4 loads)
    stgA(0, 0, 0); stgA(0, 0, 1);
    stgB(0, 0, 0); stgB(0, 0, 1);
    stgA(1, 1, 0); stgB(1, 1, 0);
    VMC(4);
    BAR();

    for (int t = 0; t < NT; ++t) {
        const int buf = t & 1, nx = buf ^ 1;
        const u16* a  = rA + buf * 16384;
        const u16* bb = rB + buf * 16384;
        bf16x8 aq[8], bq[4];
        // p-half rows are &63-duplicated: quadrant-1 A-frags equal quadrant-0's.
        const bool dupA = (MODE == 1) && (t < 8);

        // ---- phase 0: ks0, both M-quadrants ----
        #pragma unroll
        for (int i = 0; i < 4; ++i) aq[i] = ldfrag(a + i * 128);
        if (!dupA) {
            #pragma unroll
            for (int i = 0; i < 4; ++i) aq[4 + i] = ldfrag(a + (4 + i) * 128);
        }
        #pragma unroll
        for (int j = 0; j < 4; ++j) bq[j] = ldfrag(bb + j * 128);
        if (t + 1 < NT) { stgA(t + 1, nx, 1); stgB(t + 1, nx, 1); }
        BAR();
        __builtin_amdgcn_s_setprio(1);
        #pragma unroll
        for (int i = 0; i < 4; ++i)
            #pragma unroll
            for (int j = 0; j < 4; ++j)
                acc[i][j] = __builtin_amdgcn_mfma_f32_16x16x32_bf16(aq[i], bq[j], acc[i][j], 0, 0, 0);
        #pragma unroll
        for (int i = 0; i < 4; ++i) {
            const bf16x8 av = dupA ? aq[i] : aq[4 + i];
            #pragma unroll
            for (int j = 0; j < 4; ++j)
                acc[4 + i][j] = __builtin_amdgcn_mfma_f32_16x16x32_bf16(av, bq[j], acc[4 + i][j], 0, 0, 0);
        }
        __builtin_amdgcn_s_setprio(0);
        BAR();

        // ---- phase 1: ks1, both M-quadrants ----
        #pragma unroll
        for (int i = 0; i < 4; ++i) aq[i] = ldfrag(a + 8192 + i * 128);
        if (!dupA) {
            #pragma unroll
            for (int i = 0; i < 4; ++i) aq[4 + i] = ldfrag(a + 8192 + (4 + i) * 128);
        }
        #pragma unroll
        for (int j = 0; j < 4; ++j) bq[j] = ldfrag(bb + 8192 + j * 128);
        if (t + 2 < NT) { stgA(t + 2, buf, 0); stgB(t + 2, buf, 0); }
        if (t + 2 < NT) { VMC(4); } else { VMC(0); }
        BAR();
        __builtin_amdgcn_s_setprio(1);
        #pragma unroll
        for (int i = 0; i < 4; ++i)
            #pragma unroll
            for (int j = 0; j < 4; ++j)
                acc[i][j] = __builtin_amdgcn_mfma_f32_16x16x32_bf16(aq[i], bq[j], acc[i][j], 0, 0, 0);
        #pragma unroll
        for (int i = 0; i < 4; ++i) {
            const bf16x8 av = dupA ? aq[i] : aq[4 + i];
            #pragma unroll
            for (int j = 0; j < 4; ++j)
                acc[4 + i][j] = __builtin_amdgcn_mfma_f32_16x16x32_bf16(av, bq[j], acc[4 + i][j], 0, 0, 0);
        }
        __builtin_amdgcn_s_setprio(0);
        BAR();
    }

    // ---- epilogue ----
    #pragma unroll
    for (int i = 0; i < 8; ++i) {
        const int rowb = wrow0 + i * 16 + hk * 4;
        #pragma unroll
        for (int j = 0; j < 4; ++j) {
            const int col = gn0 + wcol0 + j * 16 + lm;
            float v4[4];
            #pragma unroll
            for (int r = 0; r < 4; ++r) v4[r] = acc[i][j][r];

            if constexpr (MODE == 1) {
                if (col < 512) {
                    #pragma unroll
                    for (int r = 0; r < 4; ++r) {
                        const int row = rowb + r;
                        float v = fmaxf(v4[r] + bias[col], 0.0f);
                        if (col < 256) outB[((size_t)b << 16) + (size_t)row * 256 + col] = f2bf(v);
                        else           out1[((size_t)b << 16) + (size_t)row * 256 + (col - 256)] = f2bf(v);
                    }
                } else {
                    ushort4 o;
                    o.x = f2bf(fmaxf(v4[0] + bias[col], 0.0f));
                    o.y = f2bf(fmaxf(v4[1] + bias[col], 0.0f));
                    o.z = f2bf(fmaxf(v4[2] + bias[col], 0.0f));
                    o.w = f2bf(fmaxf(v4[3] + bias[col], 0.0f));
                    *reinterpret_cast<ushort4*>(out2 + ((size_t)b << 18) +
                        (size_t)(col - 512) * 256 + rowb) = o;
                }
            } else if constexpr (MODE == 3) {
                #pragma unroll
                for (int r = 0; r < 4; ++r) {
                    const int row = rowb + r;
                    float v = v4[r];
                    float cv;
                    if (col < 512) {
                        const size_t ridx = ((size_t)b << 15) + (size_t)(row & 63) * 512 + col;
                        cv = EXf ? EXf[ridx] : bf2f(EXb[ridx]);
                    } else {
                        cv = bf2f(A1[((size_t)b << 17) + (size_t)row * 512 + (col - 512)]);
                    }
                    v += cv;
                    outB[((size_t)b << 18) + (size_t)row * 1024 + col] = f2bf(v);
                }
            } else { // 4
                #pragma unroll
                for (int r = 0; r < 4; ++r) {
                    const int row = rowb + r;
                    float v = fmaxf(v4[r] + bias[col], 0.0f);
                    outB[((size_t)b << 17) + (size_t)row * 512 + col] = f2bf(v);
                }
            }
        }
    }
}

// ============ SP kernel (R10/R11, passed): up-proj batch-pair fold =========
__global__ __launch_bounds__(512, 4)
void sp(const u16* __restrict__ A0, const u16* __restrict__ Bt,
        const float* __restrict__ bias, const float* __restrict__ EXf,
        u16* __restrict__ outB, int K)
{
    __shared__ __align__(16) u16 As[2][4096];
    __shared__ __align__(16) u16 Bs[2][8192];

    const int bz   = blockIdx.z;
    const int gn0  = blockIdx.x * 256;
    const int tid  = threadIdx.x;
    const int lane = tid & 63;
    const int w    = tid >> 6;
    const int wr   = w >> 2, wc = w & 3;
    const int wrow0 = wr * 64, wcol0 = wc * 64;
    const int lm   = lane & 15, hk = lane >> 4;
    const int NT   = K / 32;

    const int rowA = tid & 127, uA = tid >> 7;
    const int rowB = tid & 255, uB = tid >> 8;

    const u16* gA = A0 + ((size_t)(2 * bz + (rowA >> 6)) << 15)
                       + (size_t)(rowA & 63) * 512 + uA * 8;
    const u16* gB0 = Bt + (size_t)(gn0 + rowB) * K + uB * 8;
    const u16* gB1 = gB0 + 16;

    u16* dA  = &As[0][(size_t)(uA * 128 + rowA) * 8];
    u16* dB0 = &Bs[0][(size_t)(uB * 256 + rowB) * 8];
    u16* dB1 = dB0 + 4096;

    auto stage = [&](int kt, int buf) {
        const int ko = kt * 32;
        gload16(gA  + ko, dA  + buf * 4096);
        gload16(gB0 + ko, dB0 + buf * 8192);
        gload16(gB1 + ko, dB1 + buf * 8192);
    };

    const unsigned aB = ldsaddr(&As[0][0]) + (unsigned)((hk * 128 + wrow0 + lm) * 16);
    const unsigned bB = ldsaddr(&Bs[0][0]) + (unsigned)((hk * 256 + wcol0 + lm) * 16);

    f32x4 acc[4][4];
    #pragma unroll
    for (int i = 0; i < 4; ++i)
        #pragma unroll
        for (int j = 0; j < 4; ++j)
            acc[i][j] = (f32x4){0.f, 0.f, 0.f, 0.f};

    stage(0, 0);
    stage(1, 1);

    for (int t = 0; t < NT; ++t) {
        const int buf = t & 1;
        if (t == NT - 1) { VMC(0); } else { VMC(3); }
        BAR();
        bf16x8 aq[4], bq[4];
        const unsigned ab = aB + (unsigned)buf * 8192u;
        const unsigned bb = bB + (unsigned)buf * 16384u;
        #pragma unroll
        for (int i = 0; i < 4; ++i) aq[i] = dsr128(ab + (unsigned)(i * 256));
        #pragma unroll
        for (int j = 0; j < 4; ++j) bq[j] = dsr128(bb + (unsigned)(j * 256));
        LGKM(0);
        __builtin_amdgcn_s_setprio(1);
        #pragma unroll
        for (int i = 0; i < 4; ++i)
            #pragma unroll
            for (int j = 0; j < 4; ++j)
                acc[i][j] = __builtin_amdgcn_mfma_f32_16x16x32_bf16(aq[i], bq[j], acc[i][j], 0, 0, 0);
        __builtin_amdgcn_s_setprio(0);
        BAR();
        if (t + 2 < NT) stage(t + 2, buf);
    }

    #pragma unroll
    for (int i = 0; i < 4; ++i) {
        const int lrb = wrow0 + i * 16 + hk * 4;
        const int b2  = 2 * bz + (lrb >> 6);
        #pragma unroll
        for (int j = 0; j < 4; ++j) {
            const int col = gn0 + wcol0 + j * 16 + lm;
            const float wx = EXf[(size_t)512 * 512 + col];
            const float wy = EXf[(size_t)513 * 512 + col];
            const float bc = bias[col];
            #pragma unroll
            for (int r = 0; r < 4; ++r) {
                const int prow = (lrb + r) & 63;
                const float py = -0.3f + 0.04f * (float)(prow & 15);
                const float base = acc[i][j][r] + py * wy + bc;
                #pragma unroll
                for (int q = 0; q < 4; ++q) {
                    const float px = -0.3f + 0.04f * (float)((prow >> 4) + 4 * q);
                    const float v = fmaxf(base + px * wx, 0.0f);
                    outB[((size_t)b2 << 17) + (size_t)(prow + 64 * q) * 512 + col] = f2bf(v);
                }
            }
        }
    }
}

// ============ MSM kernel (R10/R11, passed): l @ h^T fused row softmax ======
__global__ __launch_bounds__(256, 1)
void msm(const u16* __restrict__ L, const u16* __restrict__ H,
         u16* __restrict__ attn)
{
    __shared__ __align__(16) u16 As[2][8192];
    __shared__ __align__(16) u16 Bs[2][16384];
    __shared__ float smax[2][2][64];
    __shared__ float ssum[2][2][64];

    const int b    = blockIdx.z;
    const int gm0  = blockIdx.y * 128;
    const int tid  = threadIdx.x;
    const int lane = tid & 63;
    const int w    = tid >> 6;
    const int wr   = w >> 1, wc = w & 1;
    const int lm   = lane & 15, hk = lane >> 4;

    auto stage = [&](int kt, int buf) {
        const int kb = kt * 64;
        #pragma unroll
        for (int t = 0; t < 4; ++t) {
            const int idx = tid + t * 256;
            const int U = idx >> 7, row = idx & 127;
            gload16(L + ((size_t)b << 16) + (size_t)(gm0 + row) * 256 + kb + U * 8,
                    &As[buf][(size_t)idx * 8]);
        }
        #pragma unroll
        for (int t = 0; t < 8; ++t) {
            const int idx = tid + t * 256;
            const int U = idx >> 8, row = idx & 255;
            gload16(H + ((size_t)b << 16) + (size_t)row * 256 + kb + U * 8,
                    &Bs[buf][(size_t)idx * 8]);
        }
    };

    f32x4 acc[4][8];
    #pragma unroll
    for (int i = 0; i < 4; ++i)
        #pragma unroll
        for (int j = 0; j < 8; ++j)
            acc[i][j] = (f32x4){0.f, 0.f, 0.f, 0.f};

    stage(0, 0);
    stage(1, 1);

    for (int kt = 0; kt < 4; ++kt) {
        const int cur = kt & 1;
        if (kt == 3) { VMC(0); } else { VMC(12); }
        BAR();
        #pragma unroll
        for (int ks = 0; ks < 2; ++ks) {
            bf16x8 aq[4], bq[8];
            #pragma unroll
            for (int i = 0; i < 4; ++i)
                aq[i] = ldfrag(&As[cur][(size_t)((ks * 4 + hk) * 128 + wr * 64 + i * 16 + lm) * 8]);
            #pragma unroll
            for (int j = 0; j < 8; ++j)
                bq[j] = ldfrag(&Bs[cur][(size_t)((ks * 4 + hk) * 256 + wc * 128 + j * 16 + lm) * 8]);
            #pragma unroll
            for (int i = 0; i < 4; ++i)
                #pragma unroll
                for (int j = 0; j < 8; ++j)
                    acc[i][j] = __builtin_amdgcn_mfma_f32_16x16x32_bf16(aq[i], bq[j], acc[i][j], 0, 0, 0);
        }
        BAR();
        if (kt + 2 < 4) stage(kt + 2, cur);
    }

    float m[4][4];
    #pragma unroll
    for (int i = 0; i < 4; ++i)
        #pragma unroll
        for (int r = 0; r < 4; ++r) {
            float mm = acc[i][0][r];
            #pragma unroll
            for (int j = 1; j < 8; ++j) mm = fmaxf(mm, acc[i][j][r]);
            #pragma unroll
            for (int o = 1; o < 16; o <<= 1) mm = fmaxf(mm, __shfl_xor(mm, o));
            m[i][r] = mm;
        }
    if (lm == 0) {
        #pragma unroll
        for (int i = 0; i < 4; ++i)
            #pragma unroll
            for (int r = 0; r < 4; ++r)
                smax[wr][wc][i * 16 + hk * 4 + r] = m[i][r];
    }
    __syncthreads();
    #pragma unroll
    for (int i = 0; i < 4; ++i)
        #pragma unroll
        for (int r = 0; r < 4; ++r) {
            const int lr = i * 16 + hk * 4 + r;
            m[i][r] = fmaxf(smax[wr][0][lr], smax[wr][1][lr]);
        }
    float sv[4][4];
    #pragma unroll
    for (int i = 0; i < 4; ++i)
        #pragma unroll
        for (int r = 0; r < 4; ++r) {
            float s = 0.f;
            #pragma unroll
            for (int j = 0; j < 8; ++j) {
                const float e = expf(acc[i][j][r] - m[i][r]);
                acc[i][j][r] = e;
                s += e;
            }
            #pragma unroll
            for (int o = 1; o < 16; o <<= 1) s += __shfl_xor(s, o);
            sv[i][r] = s;
        }
    if (lm == 0) {
        #pragma unroll
        for (int i = 0; i < 4; ++i)
            #pragma unroll
            for (int r = 0; r < 4; ++r)
                ssum[wr][wc][i * 16 + hk * 4 + r] = sv[i][r];
    }
    __syncthreads();
    #pragma unroll
    for (int i = 0; i < 4; ++i) {
        #pragma unroll
        for (int r = 0; r < 4; ++r) {
            const int lr = i * 16 + hk * 4 + r;
            const float inv = 1.0f / (ssum[wr][0][lr] + ssum[wr][1][lr]);
            const int row = gm0 + wr * 64 + lr;
            #pragma unroll
            for (int j = 0; j < 8; ++j) {
                const int col = wc * 128 + j * 16 + lm;
                attn[((size_t)b << 16) + (size_t)row * 256 + col] = f2bf(acc[i][j][r] * inv);
            }
        }
    }
}

// ============ SMALL kernel (R10/R11, passed): 128x128, BK=64 ===============
template<int MODE>
__global__ __launch_bounds__(256, 2)
void mg(const u16* __restrict__ A0, const u16* __restrict__ Bt,
        const float* __restrict__ bias, const float* __restrict__ EXf,
        float* __restrict__ outF, u16* __restrict__ outB,
        int K, long sB)
{
    constexpr int BK = 64;
    constexpr int UMASK = 7;

    __shared__ __align__(16) u16 As[2][128 * 64];
    __shared__ __align__(16) u16 Bs[2][128 * 64];

    const int b    = blockIdx.z;
    const int tid  = threadIdx.x;
    const int lane = tid & 63;
    const int w    = tid >> 6;
    const int wr   = w >> 1, wc = w & 1;
    const int wrow0 = wr * 64, wcol0 = wc * 64;
    const int gm0  = blockIdx.y * 128;
    const int gn0  = blockIdx.x * 128;
    const int lm   = lane & 15, hk = lane >> 4;
    const int NT = K / BK;

    auto stage = [&](int kt, int buf) {
        const int kb = kt * BK;
        #pragma unroll
        for (int t = 0; t < 4; ++t) {
            const int idx = tid + t * 256;
            const int row = idx >> 3, u = idx & UMASK;
            const int kk = kb + ((u ^ (row & UMASK)) << 3);
            const u16* ga;
            if constexpr (MODE == 5) {
                ga = A0 + ((size_t)b << 17) + (size_t)(gm0 + row) * 512 + kk;
            } else { // 6: reshape p1 [64][1024]
                int gr = gm0 + row; if (gr > 63) gr = 63;
                ga = A0 + ((size_t)b << 16) + (size_t)(gr * 4 + (kk >> 8)) * 256 + (kk & 255);
            }
            gload16(ga, &As[buf][(size_t)(w * 64 + t * 256) * 8]);
        }
        #pragma unroll
        for (int t = 0; t < 4; ++t) {
            const int idx = tid + t * 256;
            const int row = idx >> 3, u = idx & UMASK;
            const int kk = kb + ((u ^ (row & UMASK)) << 3);
            gload16(Bt + (size_t)b * sB + (size_t)(gn0 + row) * K + kk,
                    &Bs[buf][(size_t)(w * 64 + t * 256) * 8]);
        }
    };

    f32x4 acc[4][4];
    #pragma unroll
    for (int i = 0; i < 4; ++i)
        #pragma unroll
        for (int j = 0; j < 4; ++j)
            acc[i][j] = (f32x4){0.f, 0.f, 0.f, 0.f};

    stage(0, 0);
    if (NT > 1) stage(1, 1);

    for (int kt = 0; kt < NT; ++kt) {
        const int cur = kt & 1;
        if (kt == NT - 1) { VMC(0); } else { VMC(8); }
        __builtin_amdgcn_s_barrier();
        FENCE;

        #pragma unroll
        for (int ks = 0; ks < 2; ++ks) {
            bf16x8 af[4], bfr[4];
            #pragma unroll
            for (int i = 0; i < 4; ++i) {
                const int row = wrow0 + i * 16 + lm;
                af[i] = ldfrag(&As[cur][(size_t)row * BK + (((ks * 4 + hk) ^ (row & UMASK)) << 3)]);
            }
            #pragma unroll
            for (int j = 0; j < 4; ++j) {
                const int row = wcol0 + j * 16 + lm;
                bfr[j] = ldfrag(&Bs[cur][(size_t)row * BK + (((ks * 4 + hk) ^ (row & UMASK)) << 3)]);
            }
            __builtin_amdgcn_s_setprio(1);
            #pragma unroll
            for (int i = 0; i < 4; ++i)
                #pragma unroll
                for (int j = 0; j < 4; ++j)
                    acc[i][j] = __builtin_amdgcn_mfma_f32_16x16x32_bf16(af[i], bfr[j], acc[i][j], 0, 0, 0);
            __builtin_amdgcn_s_setprio(0);
        }

        FENCE;
        __builtin_amdgcn_s_barrier();
        if (kt + 2 < NT) stage(kt + 2, cur);
    }

    #pragma unroll
    for (int i = 0; i < 4; ++i) {
        #pragma unroll
        for (int r = 0; r < 4; ++r) {
            const int row = gm0 + wrow0 + i * 16 + hk * 4 + r;
            if (MODE == 6 && row >= 64) continue;
            #pragma unroll
            for (int j = 0; j < 4; ++j) {
                const int col = gn0 + wcol0 + j * 16 + lm;
                float v = acc[i][j][r];
                if constexpr (MODE == 5) {
                    v = fmaxf(v + bias[col], 0.0f);
                    const size_t oidx = ((size_t)b << 16) + (size_t)row * 256 + col;
                    if (EXf) v += EXf[oidx];
                    outF[oidx] = v;
                    if (outB) outB[oidx] = f2bf(v);
                } else { // 6
                    v = fmaxf(v + bias[col], 0.0f);
                    const size_t oidx = ((size_t)b << 15) + (size_t)row * 512 + col;
                    v = EXf[oidx] - v;
                    outB[oidx] = f2bf(v);
                }
            }
        }
    }
}

// ---------------- aux kernels ----------------
template<bool F32IN>
__global__ __launch_bounds__(256)
void transpose_k(const void* __restrict__ in_, u16* __restrict__ out, int R, int C)
{
    __shared__ float t[64][65];
    const size_t zo = (size_t)blockIdx.z * (size_t)R * C;
    const int c0 = blockIdx.x * 64, r0 = blockIdx.y * 64;
    const int x = threadIdx.x, y = threadIdx.y;
    #pragma unroll
    for (int i = 0; i < 16; ++i) {
        const int r = y * 16 + i;
        float v;
        if constexpr (F32IN) v = ((const float*)in_)[zo + (size_t)(r0 + r) * C + c0 + x];
        else                 v = bf2f(((const u16*)in_)[zo + (size_t)(r0 + r) * C + c0 + x]);
        t[r][x] = v;
    }
    __syncthreads();
    #pragma unroll
    for (int i = 0; i < 16; ++i) {
        const int c = y * 16 + i;
        out[zo + (size_t)(c0 + c) * R + r0 + x] = f2bf(t[x][c]);
    }
}

__global__ __launch_bounds__(256)
void cvt_k(const float* __restrict__ in, u16* __restrict__ out, int n4)
{
    int i = blockIdx.x * 256 + threadIdx.x;
    const int stride = gridDim.x * 256;
    for (; i < n4; i += stride) {
        float4 v = ((const float4*)in)[i];
        ushort4 o;
        o.x = f2bf(v.x); o.y = f2bf(v.y); o.z = f2bf(v.z); o.w = f2bf(v.w);
        ((ushort4*)out)[i] = o;
    }
}

__global__ __launch_bounds__(512)
void concat3_k(const float* __restrict__ a, const float* __restrict__ bb,
               const float* __restrict__ c, float* __restrict__ o)
{
    const int i = blockIdx.x * 512 + threadIdx.x;
    if (i < 256)       o[i] = a[i];
    else if (i < 512)  o[i] = bb[i - 256];
    else if (i < 1536) o[i] = c[i - 512];
}

extern "C" void kernel_launch(void* const* d_in, const int* in_sizes, int n_in,
                              void* d_out, int out_size, void* d_ws, size_t ws_size,
                              hipStream_t stream)
{
    const float* p      = (const float*)d_in[0];
    const float* W_up   = (const float*)d_in[1];
    const float* b_up   = (const float*)d_in[2];
    const float* Wh     = (const float*)d_in[3];
    const float* bh     = (const float*)d_in[4];
    const float* Wl     = (const float*)d_in[5];
    const float* bl     = (const float*)d_in[6];
    const float* Wg     = (const float*)d_in[7];
    const float* bg_    = (const float*)d_in[8];
    const float* Wf1    = (const float*)d_in[9];
    const float* bf1    = (const float*)d_in[10];
    const float* Wf2    = (const float*)d_in[11];
    const float* bf2v   = (const float*)d_in[12];
    const float* W_down = (const float*)d_in[13];
    const float* b_down = (const float*)d_in[14];

    const int B = in_sizes[0] / 32768;
    float* out = (float*)d_out;

    char* wsp = (char*)d_ws;
    auto alloc = [&](size_t bytes) -> char* {
        char* r = wsp; wsp += (bytes + 255) & ~(size_t)255; return r;
    };

    // ---- fixed buffers ----
    u16* WupT  = (u16*)alloc((size_t)512 * 512 * 2);
    u16* WhlgT = (u16*)alloc((size_t)1536 * 1024 * 2);
    u16* Wf1T  = (u16*)alloc((size_t)512 * 1024 * 2);
    u16* Wf2T  = (u16*)alloc((size_t)256 * 512 * 2);
    u16* WdT   = (u16*)alloc((size_t)512 * 1024 * 2);
    float* bias_hlg = (float*)alloc((size_t)1536 * 4);
    u16* pbf   = (u16*)alloc((size_t)B * 32768 * 2);

    const size_t fixed_used = (size_t)(wsp - (char*)d_ws);
    const size_t perB = 1903104;
    int BC = B;
    while (BC > 1 && fixed_used + (size_t)BC * perB + 4096 > ws_size) BC >>= 1;

    u16* upout = (u16*)alloc((size_t)BC * 131072 * 2);
    u16* gT    = (u16*)alloc((size_t)BC * 262144 * 2);
    u16* xb    = (u16*)alloc((size_t)BC * 262144 * 2);
    u16* hb    = (u16*)alloc((size_t)BC * 65536 * 2);
    u16* lb    = (u16*)alloc((size_t)BC * 65536 * 2);
    u16* atb   = (u16*)alloc((size_t)BC * 65536 * 2);
    u16* p1bf  = (u16*)alloc((size_t)BC * 65536 * 2);
    u16* pdbf  = (u16*)alloc((size_t)BC * 32768 * 2);

    const dim3 tb(64, 4);
    // ---- startup (once) ----
    {
        int n4 = B * 8192;
        int nb = (n4 + 255) / 256; if (nb > 2048) nb = 2048;
        cvt_k<<<dim3(nb), dim3(256), 0, stream>>>(p, pbf, n4);
        transpose_k<true><<<dim3(8, 8, 1),  tb, 0, stream>>>(W_up, WupT, 512, 512);
        transpose_k<true><<<dim3(4, 16, 1), tb, 0, stream>>>(Wh, WhlgT, 1024, 256);
        transpose_k<true><<<dim3(4, 16, 1), tb, 0, stream>>>(Wl, WhlgT + (size_t)256 * 1024, 1024, 256);
        transpose_k<true><<<dim3(16, 16, 1),tb, 0, stream>>>(Wg, WhlgT + (size_t)512 * 1024, 1024, 1024);
        transpose_k<true><<<dim3(8, 16, 1), tb, 0, stream>>>(Wf1, Wf1T, 1024, 512);
        transpose_k<true><<<dim3(4, 8, 1),  tb, 0, stream>>>(Wf2, Wf2T, 512, 256);
        transpose_k<true><<<dim3(8, 16, 1), tb, 0, stream>>>(W_down, WdT, 1024, 512);
        concat3_k<<<dim3(3), dim3(512), 0, stream>>>(bh, bl, bg_, bias_hlg);
    }

    auto run_up = [&](const u16* pin_bf, const float* pin_f32, const u16* pin_ebf,
                      float* f2outF, u16* f2outB, const float* f2EXf, int bc) {
        sp<<<dim3(2, 1, bc / 2), dim3(512), 0, stream>>>(
            pin_bf, WupT, b_up, W_up, upout, 512);
        bp<1><<<dim3(6, bc), dim3(512), 0, stream>>>(
            pin_bf, upout, WhlgT, bias_hlg, nullptr, nullptr, hb, lb, gT, 1024, 0);
        msm<<<dim3(1, 2, bc), dim3(256), 0, stream>>>(lb, hb, atb);
        bp<3><<<dim3(4, bc), dim3(512), 0, stream>>>(
            atb, upout, gT, nullptr, pin_f32, pin_ebf, xb, nullptr, nullptr, 256, 262144);
        bp<4><<<dim3(2, bc), dim3(512), 0, stream>>>(
            xb, nullptr, Wf1T, bf1, nullptr, nullptr, upout, nullptr, nullptr, 1024, 0);
        mg<5><<<dim3(2, 2, bc), dim3(256), 0, stream>>>(
            upout, Wf2T, bf2v, f2EXf, f2outF, f2outB, 512, 0);
    };

    for (int b0 = 0; b0 < B; b0 += BC) {
        const int bc = (B - b0 < BC) ? (B - b0) : BC;
        const u16*   pin_bf  = pbf + (size_t)b0 * 32768;
        const float* pin_f32 = p   + (size_t)b0 * 32768;
        float* outc = out + (size_t)b0 * 65536;
        run_up(pin_bf, pin_f32, nullptr, outc, p1bf, nullptr, bc);
        mg<6><<<dim3(4, 1, bc), dim3(256), 0, stream>>>(
            p1bf, WdT, b_down, pin_f32, nullptr, pdbf, 1024, 0);
        run_up(pdbf, nullptr, pdbf, outc, nullptr, outc, bc);
    }
}

// Round 14
// 831.462 us; speedup vs baseline: 1.0403x; 1.0403x over previous
//
#include <hip/hip_runtime.h>
#include <cstdint>
#include <cstddef>

// FoldingBlock round 13: consolidation — exact revert to the round-11 best
// (835us): R6 4-phase 256^2 bp core + dupA reuse + XCD-chunked swizzle,
// sp batch-pair-folded up-proj, msm fused logits+softmax, mg 128^2 small GEMM.
// (R12's merged-phase variant regressed: fine-phase interleave is the
// mechanism, not barrier count.)
// p1 = up(p); pdelta = p - down(p1); out = p1 + up(pdelta)

typedef unsigned short u16;
typedef __bf16 bf16x8 __attribute__((ext_vector_type(8)));
typedef float f32x4 __attribute__((ext_vector_type(4)));

__device__ __forceinline__ u16 f2bf(float f) {
    unsigned u = __builtin_bit_cast(unsigned, f);
    unsigned r = (u + 0x7fffu + ((u >> 16) & 1u)) >> 16;
    return (u16)r;
}
__device__ __forceinline__ float bf2f(u16 h) {
    unsigned u = ((unsigned)h) << 16;
    return __builtin_bit_cast(float, u);
}
__device__ __forceinline__ bf16x8 ldfrag(const u16* p) {
    return __builtin_bit_cast(bf16x8, *reinterpret_cast<const uint4*>(p));
}
__device__ __forceinline__ void gload16(const u16* g, u16* l) {
    __builtin_amdgcn_global_load_lds((__attribute__((address_space(1))) void*)g,
                                     (__attribute__((address_space(3))) void*)l,
                                     16, 0, 0);
}
__device__ __forceinline__ unsigned ldsaddr(const u16* p) {
    return (unsigned)(size_t)(const __attribute__((address_space(3))) u16*)p;
}
__device__ __forceinline__ bf16x8 dsr128(unsigned a) {
    f32x4 r;
    asm volatile("ds_read_b128 %0, %1" : "=v"(r) : "v"(a));
    return __builtin_bit_cast(bf16x8, r);
}

#define FENCE asm volatile("" ::: "memory")
#define BAR() do { FENCE; __builtin_amdgcn_s_barrier(); FENCE; } while (0)
#define VMC(N) asm volatile("s_waitcnt vmcnt(" #N ")" ::: "memory")
#define LGKM(N) do { asm volatile("s_waitcnt lgkmcnt(" #N ")" ::: "memory"); \
                     __builtin_amdgcn_sched_barrier(0); } while (0)

// XCD-chunked swizzle: same chunk of logical ids lands on one XCD (8 XCDs).
__device__ __forceinline__ int xcd_swz(int lin, int nwg) {
    if ((nwg & 7) == 0) { const int q = nwg >> 3; lin = (lin & 7) * q + (lin >> 3); }
    return lin;
}

// ================= BIG kernel (R6/R10 base): BM=256, BN=256, BK=64 =========
// Modes: 1 HLG (A=cat(p,upout) K=1024 -> h,l,gT), 3 X, 4 F1.
template<int MODE>
__global__ __launch_bounds__(512, 1)
void bp(const u16* __restrict__ A0, const u16* __restrict__ A1,
        const u16* __restrict__ Bt, const float* __restrict__ bias,
        const float* __restrict__ EXf, const u16* __restrict__ EXb,
        u16* __restrict__ outB, u16* __restrict__ out1, u16* __restrict__ out2,
        int K, long sB)
{
    __shared__ __align__(16) u16 As[2][16384];
    __shared__ __align__(16) u16 Bs[2][16384];

    const int lin = xcd_swz(blockIdx.y * gridDim.x + blockIdx.x,
                            gridDim.x * gridDim.y);
    const int b    = lin / gridDim.x;
    const int gn0  = (lin % gridDim.x) * 256;
    const int tid  = threadIdx.x;
    const int lane = tid & 63;
    const int w    = tid >> 6;
    const int wr   = w >> 2, wc = w & 3;
    const int wrow0 = wr * 128, wcol0 = wc * 64;
    const int lm   = lane & 15, hk = lane >> 4;
    const int NT   = K / 64;

    const int srow = tid & 255;
    const int su   = tid >> 8;

    const u16* gA0;
    const u16* gA1 = nullptr;
    if constexpr (MODE == 1) {
        gA0 = A0 + ((size_t)b << 15) + (size_t)(srow & 63) * 512 + su * 8;
        gA1 = A1 + ((size_t)b << 17) + (size_t)srow * 512 + su * 8;
    } else if constexpr (MODE == 3) {
        gA0 = A0 + ((size_t)b << 16) + (size_t)srow * 256 + su * 8;
    } else { // 4
        gA0 = A0 + ((size_t)b << 18) + (size_t)srow * 1024 + su * 8;
    }
    const u16* gB0 = Bt + (size_t)b * sB + (size_t)(gn0 + srow) * K + su * 8;

    u16* dA = &As[0][(size_t)(su * 256 + srow) * 8];
    u16* dB = &Bs[0][(size_t)(su * 256 + srow) * 8];

    auto stgA = [&](int kt, int buf, int rp) {
        const u16* g;
        if constexpr (MODE == 1) g = (kt < 8) ? (gA0 + kt * 64) : (gA1 + (kt - 8) * 64);
        else                     g = gA0 + kt * 64;
        u16* d = dA + buf * 16384 + rp * 8192;
        gload16(g + rp * 32,      d);
        gload16(g + rp * 32 + 16, d + 4096);
    };
    auto stgB = [&](int kt, int buf, int rp) {
        const u16* g = gB0 + kt * 64 + rp * 32;
        u16* d = dB + buf * 16384 + rp * 8192;
        gload16(g,      d);
        gload16(g + 16, d + 4096);
    };

    const u16* rA = &As[0][(size_t)(hk * 256 + wrow0 + lm) * 8];
    const u16* rB = &Bs[0][(size_t)(hk * 256 + wcol0 + lm) * 8];

    f32x4 acc[8][4];
    #pragma unroll
    for (int i = 0; i < 8; ++i)
        #pragma unroll
        for (int j = 0; j < 4; ++j)
            acc[i][j] = (f32x4){0.f, 0.f, 0.f, 0.f};

    stgA(0, 0, 0); stgA(0, 0, 1);
    stgB(0, 0, 0); stgB(0, 0, 1);
    stgA(1, 1, 0); stgB(1, 1, 0);
    VMC(4);
    BAR();

    for (int t = 0; t < NT; ++t) {
        const int buf = t & 1, nx = buf ^ 1;
        const u16* a  = rA + buf * 16384;
        const u16* bb = rB + buf * 16384;
        bf16x8 aq[4], bq[4];
        // p-half rows are &63-duplicated: quadrant-1 A-frags equal quadrant-0's.
        const bool dupA = (MODE == 1) && (t < 8);

        #pragma unroll
        for (int i = 0; i < 4; ++i) aq[i] = ldfrag(a + i * 128);
        #pragma unroll
        for (int j = 0; j < 4; ++j) bq[j] = ldfrag(bb + j * 128);
        if (t + 1 < NT) stgA(t + 1, nx, 1);
        BAR();
        __builtin_amdgcn_s_setprio(1);
        #pragma unroll
        for (int i = 0; i < 4; ++i)
            #pragma unroll
            for (int j = 0; j < 4; ++j)
                acc[i][j] = __builtin_amdgcn_mfma_f32_16x16x32_bf16(aq[i], bq[j], acc[i][j], 0, 0, 0);
        __builtin_amdgcn_s_setprio(0);
        BAR();

        if (!dupA) {
            #pragma unroll
            for (int i = 0; i < 4; ++i) aq[i] = ldfrag(a + (4 + i) * 128);
        }
        if (t + 1 < NT) stgB(t + 1, nx, 1);
        BAR();
        __builtin_amdgcn_s_setprio(1);
        #pragma unroll
        for (int i = 0; i < 4; ++i)
            #pragma unroll
            for (int j = 0; j < 4; ++j)
                acc[4 + i][j] = __builtin_amdgcn_mfma_f32_16x16x32_bf16(aq[i], bq[j], acc[4 + i][j], 0, 0, 0);
        __builtin_amdgcn_s_setprio(0);
        BAR();

        #pragma unroll
        for (int i = 0; i < 4; ++i) aq[i] = ldfrag(a + 8192 + i * 128);
        #pragma unroll
        for (int j = 0; j < 4; ++j) bq[j] = ldfrag(bb + 8192 + j * 128);
        if (t + 2 < NT) stgA(t + 2, buf, 0);
        BAR();
        __builtin_amdgcn_s_setprio(1);
        #pragma unroll
        for (int i = 0; i < 4; ++i)
            #pragma unroll
            for (int j = 0; j < 4; ++j)
                acc[i][j] = __builtin_amdgcn_mfma_f32_16x16x32_bf16(aq[i], bq[j], acc[i][j], 0, 0, 0);
        __builtin_amdgcn_s_setprio(0);
        BAR();

        if (!dupA) {
            #pragma unroll
            for (int i = 0; i < 4; ++i) aq[i] = ldfrag(a + 8192 + (4 + i) * 128);
        }
        if (t + 2 < NT) stgB(t + 2, buf, 0);
        if (t + 2 < NT) { VMC(4); } else { VMC(0); }
        BAR();
        __builtin_amdgcn_s_setprio(1);
        #pragma unroll
        for (int i = 0; i < 4; ++i)
            #pragma unroll
            for (int j = 0; j < 4; ++j)
                acc[4 + i][j] = __builtin_amdgcn_mfma_f32_16x16x32_bf16(aq[i], bq[j], acc[4 + i][j], 0, 0, 0);
        __builtin_amdgcn_s_setprio(0);
        BAR();
    }

    #pragma unroll
    for (int i = 0; i < 8; ++i) {
        const int rowb = wrow0 + i * 16 + hk * 4;
        #pragma unroll
        for (int j = 0; j < 4; ++j) {
            const int col = gn0 + wcol0 + j * 16 + lm;
            float v4[4];
            #pragma unroll
            for (int r = 0; r < 4; ++r) v4[r] = acc[i][j][r];

            if constexpr (MODE == 1) {
                if (col < 512) {
                    #pragma unroll
                    for (int r = 0; r < 4; ++r) {
                        const int row = rowb + r;
                        float v = fmaxf(v4[r] + bias[col], 0.0f);
                        if (col < 256) outB[((size_t)b << 16) + (size_t)row * 256 + col] = f2bf(v);
                        else           out1[((size_t)b << 16) + (size_t)row * 256 + (col - 256)] = f2bf(v);
                    }
                } else {
                    ushort4 o;
                    o.x = f2bf(fmaxf(v4[0] + bias[col], 0.0f));
                    o.y = f2bf(fmaxf(v4[1] + bias[col], 0.0f));
                    o.z = f2bf(fmaxf(v4[2] + bias[col], 0.0f));
                    o.w = f2bf(fmaxf(v4[3] + bias[col], 0.0f));
                    *reinterpret_cast<ushort4*>(out2 + ((size_t)b << 18) +
                        (size_t)(col - 512) * 256 + rowb) = o;
                }
            } else if constexpr (MODE == 3) {
                #pragma unroll
                for (int r = 0; r < 4; ++r) {
                    const int row = rowb + r;
                    float v = v4[r];
                    float cv;
                    if (col < 512) {
                        const size_t ridx = ((size_t)b << 15) + (size_t)(row & 63) * 512 + col;
                        cv = EXf ? EXf[ridx] : bf2f(EXb[ridx]);
                    } else {
                        cv = bf2f(A1[((size_t)b << 17) + (size_t)row * 512 + (col - 512)]);
                    }
                    v += cv;
                    outB[((size_t)b << 18) + (size_t)row * 1024 + col] = f2bf(v);
                }
            } else { // 4
                #pragma unroll
                for (int r = 0; r < 4; ++r) {
                    const int row = rowb + r;
                    float v = fmaxf(v4[r] + bias[col], 0.0f);
                    outB[((size_t)b << 17) + (size_t)row * 512 + col] = f2bf(v);
                }
            }
        }
    }
}

// ============ SP kernel (R10, passed): up-proj batch-pair fold =============
__global__ __launch_bounds__(512, 4)
void sp(const u16* __restrict__ A0, const u16* __restrict__ Bt,
        const float* __restrict__ bias, const float* __restrict__ EXf,
        u16* __restrict__ outB, int K)
{
    __shared__ __align__(16) u16 As[2][4096];
    __shared__ __align__(16) u16 Bs[2][8192];

    const int bz   = blockIdx.z;
    const int gn0  = blockIdx.x * 256;
    const int tid  = threadIdx.x;
    const int lane = tid & 63;
    const int w    = tid >> 6;
    const int wr   = w >> 2, wc = w & 3;
    const int wrow0 = wr * 64, wcol0 = wc * 64;
    const int lm   = lane & 15, hk = lane >> 4;
    const int NT   = K / 32;

    const int rowA = tid & 127, uA = tid >> 7;
    const int rowB = tid & 255, uB = tid >> 8;

    const u16* gA = A0 + ((size_t)(2 * bz + (rowA >> 6)) << 15)
                       + (size_t)(rowA & 63) * 512 + uA * 8;
    const u16* gB0 = Bt + (size_t)(gn0 + rowB) * K + uB * 8;
    const u16* gB1 = gB0 + 16;

    u16* dA  = &As[0][(size_t)(uA * 128 + rowA) * 8];
    u16* dB0 = &Bs[0][(size_t)(uB * 256 + rowB) * 8];
    u16* dB1 = dB0 + 4096;

    auto stage = [&](int kt, int buf) {
        const int ko = kt * 32;
        gload16(gA  + ko, dA  + buf * 4096);
        gload16(gB0 + ko, dB0 + buf * 8192);
        gload16(gB1 + ko, dB1 + buf * 8192);
    };

    const unsigned aB = ldsaddr(&As[0][0]) + (unsigned)((hk * 128 + wrow0 + lm) * 16);
    const unsigned bB = ldsaddr(&Bs[0][0]) + (unsigned)((hk * 256 + wcol0 + lm) * 16);

    f32x4 acc[4][4];
    #pragma unroll
    for (int i = 0; i < 4; ++i)
        #pragma unroll
        for (int j = 0; j < 4; ++j)
            acc[i][j] = (f32x4){0.f, 0.f, 0.f, 0.f};

    stage(0, 0);
    stage(1, 1);

    for (int t = 0; t < NT; ++t) {
        const int buf = t & 1;
        if (t == NT - 1) { VMC(0); } else { VMC(3); }
        BAR();
        bf16x8 aq[4], bq[4];
        const unsigned ab = aB + (unsigned)buf * 8192u;
        const unsigned bb = bB + (unsigned)buf * 16384u;
        #pragma unroll
        for (int i = 0; i < 4; ++i) aq[i] = dsr128(ab + (unsigned)(i * 256));
        #pragma unroll
        for (int j = 0; j < 4; ++j) bq[j] = dsr128(bb + (unsigned)(j * 256));
        LGKM(0);
        __builtin_amdgcn_s_setprio(1);
        #pragma unroll
        for (int i = 0; i < 4; ++i)
            #pragma unroll
            for (int j = 0; j < 4; ++j)
                acc[i][j] = __builtin_amdgcn_mfma_f32_16x16x32_bf16(aq[i], bq[j], acc[i][j], 0, 0, 0);
        __builtin_amdgcn_s_setprio(0);
        BAR();
        if (t + 2 < NT) stage(t + 2, buf);
    }

    #pragma unroll
    for (int i = 0; i < 4; ++i) {
        const int lrb = wrow0 + i * 16 + hk * 4;
        const int b2  = 2 * bz + (lrb >> 6);
        #pragma unroll
        for (int j = 0; j < 4; ++j) {
            const int col = gn0 + wcol0 + j * 16 + lm;
            const float wx = EXf[(size_t)512 * 512 + col];
            const float wy = EXf[(size_t)513 * 512 + col];
            const float bc = bias[col];
            #pragma unroll
            for (int r = 0; r < 4; ++r) {
                const int prow = (lrb + r) & 63;
                const float py = -0.3f + 0.04f * (float)(prow & 15);
                const float base = acc[i][j][r] + py * wy + bc;
                #pragma unroll
                for (int q = 0; q < 4; ++q) {
                    const float px = -0.3f + 0.04f * (float)((prow >> 4) + 4 * q);
                    const float v = fmaxf(base + px * wx, 0.0f);
                    outB[((size_t)b2 << 17) + (size_t)(prow + 64 * q) * 512 + col] = f2bf(v);
                }
            }
        }
    }
}

// ============ MSM kernel (R10, passed): l @ h^T fused row softmax ==========
__global__ __launch_bounds__(256, 1)
void msm(const u16* __restrict__ L, const u16* __restrict__ H,
         u16* __restrict__ attn)
{
    __shared__ __align__(16) u16 As[2][8192];
    __shared__ __align__(16) u16 Bs[2][16384];
    __shared__ float smax[2][2][64];
    __shared__ float ssum[2][2][64];

    const int b    = blockIdx.z;
    const int gm0  = blockIdx.y * 128;
    const int tid  = threadIdx.x;
    const int lane = tid & 63;
    const int w    = tid >> 6;
    const int wr   = w >> 1, wc = w & 1;
    const int lm   = lane & 15, hk = lane >> 4;

    auto stage = [&](int kt, int buf) {
        const int kb = kt * 64;
        #pragma unroll
        for (int t = 0; t < 4; ++t) {
            const int idx = tid + t * 256;
            const int U = idx >> 7, row = idx & 127;
            gload16(L + ((size_t)b << 16) + (size_t)(gm0 + row) * 256 + kb + U * 8,
                    &As[buf][(size_t)idx * 8]);
        }
        #pragma unroll
        for (int t = 0; t < 8; ++t) {
            const int idx = tid + t * 256;
            const int U = idx >> 8, row = idx & 255;
            gload16(H + ((size_t)b << 16) + (size_t)row * 256 + kb + U * 8,
                    &Bs[buf][(size_t)idx * 8]);
        }
    };

    f32x4 acc[4][8];
    #pragma unroll
    for (int i = 0; i < 4; ++i)
        #pragma unroll
        for (int j = 0; j < 8; ++j)
            acc[i][j] = (f32x4){0.f, 0.f, 0.f, 0.f};

    stage(0, 0);
    stage(1, 1);

    for (int kt = 0; kt < 4; ++kt) {
        const int cur = kt & 1;
        if (kt == 3) { VMC(0); } else { VMC(12); }
        BAR();
        #pragma unroll
        for (int ks = 0; ks < 2; ++ks) {
            bf16x8 aq[4], bq[8];
            #pragma unroll
            for (int i = 0; i < 4; ++i)
                aq[i] = ldfrag(&As[cur][(size_t)((ks * 4 + hk) * 128 + wr * 64 + i * 16 + lm) * 8]);
            #pragma unroll
            for (int j = 0; j < 8; ++j)
                bq[j] = ldfrag(&Bs[cur][(size_t)((ks * 4 + hk) * 256 + wc * 128 + j * 16 + lm) * 8]);
            #pragma unroll
            for (int i = 0; i < 4; ++i)
                #pragma unroll
                for (int j = 0; j < 8; ++j)
                    acc[i][j] = __builtin_amdgcn_mfma_f32_16x16x32_bf16(aq[i], bq[j], acc[i][j], 0, 0, 0);
        }
        BAR();
        if (kt + 2 < 4) stage(kt + 2, cur);
    }

    float m[4][4];
    #pragma unroll
    for (int i = 0; i < 4; ++i)
        #pragma unroll
        for (int r = 0; r < 4; ++r) {
            float mm = acc[i][0][r];
            #pragma unroll
            for (int j = 1; j < 8; ++j) mm = fmaxf(mm, acc[i][j][r]);
            #pragma unroll
            for (int o = 1; o < 16; o <<= 1) mm = fmaxf(mm, __shfl_xor(mm, o));
            m[i][r] = mm;
        }
    if (lm == 0) {
        #pragma unroll
        for (int i = 0; i < 4; ++i)
            #pragma unroll
            for (int r = 0; r < 4; ++r)
                smax[wr][wc][i * 16 + hk * 4 + r] = m[i][r];
    }
    __syncthreads();
    #pragma unroll
    for (int i = 0; i < 4; ++i)
        #pragma unroll
        for (int r = 0; r < 4; ++r) {
            const int lr = i * 16 + hk * 4 + r;
            m[i][r] = fmaxf(smax[wr][0][lr], smax[wr][1][lr]);
        }
    float sv[4][4];
    #pragma unroll
    for (int i = 0; i < 4; ++i)
        #pragma unroll
        for (int r = 0; r < 4; ++r) {
            float s = 0.f;
            #pragma unroll
            for (int j = 0; j < 8; ++j) {
                const float e = expf(acc[i][j][r] - m[i][r]);
                acc[i][j][r] = e;
                s += e;
            }
            #pragma unroll
            for (int o = 1; o < 16; o <<= 1) s += __shfl_xor(s, o);
            sv[i][r] = s;
        }
    if (lm == 0) {
        #pragma unroll
        for (int i = 0; i < 4; ++i)
            #pragma unroll
            for (int r = 0; r < 4; ++r)
                ssum[wr][wc][i * 16 + hk * 4 + r] = sv[i][r];
    }
    __syncthreads();
    #pragma unroll
    for (int i = 0; i < 4; ++i) {
        #pragma unroll
        for (int r = 0; r < 4; ++r) {
            const int lr = i * 16 + hk * 4 + r;
            const float inv = 1.0f / (ssum[wr][0][lr] + ssum[wr][1][lr]);
            const int row = gm0 + wr * 64 + lr;
            #pragma unroll
            for (int j = 0; j < 8; ++j) {
                const int col = wc * 128 + j * 16 + lm;
                attn[((size_t)b << 16) + (size_t)row * 256 + col] = f2bf(acc[i][j][r] * inv);
            }
        }
    }
}

// ============ SMALL kernel (R10, passed): 128x128, BK=64 ===================
template<int MODE>
__global__ __launch_bounds__(256, 2)
void mg(const u16* __restrict__ A0, const u16* __restrict__ Bt,
        const float* __restrict__ bias, const float* __restrict__ EXf,
        float* __restrict__ outF, u16* __restrict__ outB,
        int K, long sB)
{
    constexpr int BK = 64;
    constexpr int UMASK = 7;

    __shared__ __align__(16) u16 As[2][128 * 64];
    __shared__ __align__(16) u16 Bs[2][128 * 64];

    const int b    = blockIdx.z;
    const int tid  = threadIdx.x;
    const int lane = tid & 63;
    const int w    = tid >> 6;
    const int wr   = w >> 1, wc = w & 1;
    const int wrow0 = wr * 64, wcol0 = wc * 64;
    const int gm0  = blockIdx.y * 128;
    const int gn0  = blockIdx.x * 128;
    const int lm   = lane & 15, hk = lane >> 4;
    const int NT = K / BK;

    auto stage = [&](int kt, int buf) {
        const int kb = kt * BK;
        #pragma unroll
        for (int t = 0; t < 4; ++t) {
            const int idx = tid + t * 256;
            const int row = idx >> 3, u = idx & UMASK;
            const int kk = kb + ((u ^ (row & UMASK)) << 3);
            const u16* ga;
            if constexpr (MODE == 5) {
                ga = A0 + ((size_t)b << 17) + (size_t)(gm0 + row) * 512 + kk;
            } else { // 6: reshape p1 [64][1024]
                int gr = gm0 + row; if (gr > 63) gr = 63;
                ga = A0 + ((size_t)b << 16) + (size_t)(gr * 4 + (kk >> 8)) * 256 + (kk & 255);
            }
            gload16(ga, &As[buf][(size_t)(w * 64 + t * 256) * 8]);
        }
        #pragma unroll
        for (int t = 0; t < 4; ++t) {
            const int idx = tid + t * 256;
            const int row = idx >> 3, u = idx & UMASK;
            const int kk = kb + ((u ^ (row & UMASK)) << 3);
            gload16(Bt + (size_t)b * sB + (size_t)(gn0 + row) * K + kk,
                    &Bs[buf][(size_t)(w * 64 + t * 256) * 8]);
        }
    };

    f32x4 acc[4][4];
    #pragma unroll
    for (int i = 0; i < 4; ++i)
        #pragma unroll
        for (int j = 0; j < 4; ++j)
            acc[i][j] = (f32x4){0.f, 0.f, 0.f, 0.f};

    stage(0, 0);
    if (NT > 1) stage(1, 1);

    for (int kt = 0; kt < NT; ++kt) {
        const int cur = kt & 1;
        if (kt == NT - 1) { VMC(0); } else { VMC(8); }
        __builtin_amdgcn_s_barrier();
        FENCE;

        #pragma unroll
        for (int ks = 0; ks < 2; ++ks) {
            bf16x8 af[4], bfr[4];
            #pragma unroll
            for (int i = 0; i < 4; ++i) {
                const int row = wrow0 + i * 16 + lm;
                af[i] = ldfrag(&As[cur][(size_t)row * BK + (((ks * 4 + hk) ^ (row & UMASK)) << 3)]);
            }
            #pragma unroll
            for (int j = 0; j < 4; ++j) {
                const int row = wcol0 + j * 16 + lm;
                bfr[j] = ldfrag(&Bs[cur][(size_t)row * BK + (((ks * 4 + hk) ^ (row & UMASK)) << 3)]);
            }
            __builtin_amdgcn_s_setprio(1);
            #pragma unroll
            for (int i = 0; i < 4; ++i)
                #pragma unroll
                for (int j = 0; j < 4; ++j)
                    acc[i][j] = __builtin_amdgcn_mfma_f32_16x16x32_bf16(af[i], bfr[j], acc[i][j], 0, 0, 0);
            __builtin_amdgcn_s_setprio(0);
        }

        FENCE;
        __builtin_amdgcn_s_barrier();
        if (kt + 2 < NT) stage(kt + 2, cur);
    }

    #pragma unroll
    for (int i = 0; i < 4; ++i) {
        #pragma unroll
        for (int r = 0; r < 4; ++r) {
            const int row = gm0 + wrow0 + i * 16 + hk * 4 + r;
            if (MODE == 6 && row >= 64) continue;
            #pragma unroll
            for (int j = 0; j < 4; ++j) {
                const int col = gn0 + wcol0 + j * 16 + lm;
                float v = acc[i][j][r];
                if constexpr (MODE == 5) {
                    v = fmaxf(v + bias[col], 0.0f);
                    const size_t oidx = ((size_t)b << 16) + (size_t)row * 256 + col;
                    if (EXf) v += EXf[oidx];
                    outF[oidx] = v;
                    if (outB) outB[oidx] = f2bf(v);
                } else { // 6
                    v = fmaxf(v + bias[col], 0.0f);
                    const size_t oidx = ((size_t)b << 15) + (size_t)row * 512 + col;
                    v = EXf[oidx] - v;
                    outB[oidx] = f2bf(v);
                }
            }
        }
    }
}

// ---------------- aux kernels ----------------
template<bool F32IN>
__global__ __launch_bounds__(256)
void transpose_k(const void* __restrict__ in_, u16* __restrict__ out, int R, int C)
{
    __shared__ float t[64][65];
    const size_t zo = (size_t)blockIdx.z * (size_t)R * C;
    const int c0 = blockIdx.x * 64, r0 = blockIdx.y * 64;
    const int x = threadIdx.x, y = threadIdx.y;
    #pragma unroll
    for (int i = 0; i < 16; ++i) {
        const int r = y * 16 + i;
        float v;
        if constexpr (F32IN) v = ((const float*)in_)[zo + (size_t)(r0 + r) * C + c0 + x];
        else                 v = bf2f(((const u16*)in_)[zo + (size_t)(r0 + r) * C + c0 + x]);
        t[r][x] = v;
    }
    __syncthreads();
    #pragma unroll
    for (int i = 0; i < 16; ++i) {
        const int c = y * 16 + i;
        out[zo + (size_t)(c0 + c) * R + r0 + x] = f2bf(t[x][c]);
    }
}

__global__ __launch_bounds__(256)
void cvt_k(const float* __restrict__ in, u16* __restrict__ out, int n4)
{
    int i = blockIdx.x * 256 + threadIdx.x;
    const int stride = gridDim.x * 256;
    for (; i < n4; i += stride) {
        float4 v = ((const float4*)in)[i];
        ushort4 o;
        o.x = f2bf(v.x); o.y = f2bf(v.y); o.z = f2bf(v.z); o.w = f2bf(v.w);
        ((ushort4*)out)[i] = o;
    }
}

__global__ __launch_bounds__(512)
void concat3_k(const float* __restrict__ a, const float* __restrict__ bb,
               const float* __restrict__ c, float* __restrict__ o)
{
    const int i = blockIdx.x * 512 + threadIdx.x;
    if (i < 256)       o[i] = a[i];
    else if (i < 512)  o[i] = bb[i - 256];
    else if (i < 1536) o[i] = c[i - 512];
}

extern "C" void kernel_launch(void* const* d_in, const int* in_sizes, int n_in,
                              void* d_out, int out_size, void* d_ws, size_t ws_size,
                              hipStream_t stream)
{
    const float* p      = (const float*)d_in[0];
    const float* W_up   = (const float*)d_in[1];
    const float* b_up   = (const float*)d_in[2];
    const float* Wh     = (const float*)d_in[3];
    const float* bh     = (const float*)d_in[4];
    const float* Wl     = (const float*)d_in[5];
    const float* bl     = (const float*)d_in[6];
    const float* Wg     = (const float*)d_in[7];
    const float* bg_    = (const float*)d_in[8];
    const float* Wf1    = (const float*)d_in[9];
    const float* bf1    = (const float*)d_in[10];
    const float* Wf2    = (const float*)d_in[11];
    const float* bf2v   = (const float*)d_in[12];
    const float* W_down = (const float*)d_in[13];
    const float* b_down = (const float*)d_in[14];

    const int B = in_sizes[0] / 32768;
    float* out = (float*)d_out;

    char* wsp = (char*)d_ws;
    auto alloc = [&](size_t bytes) -> char* {
        char* r = wsp; wsp += (bytes + 255) & ~(size_t)255; return r;
    };

    // ---- fixed buffers ----
    u16* WupT  = (u16*)alloc((size_t)512 * 512 * 2);
    u16* WhlgT = (u16*)alloc((size_t)1536 * 1024 * 2);
    u16* Wf1T  = (u16*)alloc((size_t)512 * 1024 * 2);
    u16* Wf2T  = (u16*)alloc((size_t)256 * 512 * 2);
    u16* WdT   = (u16*)alloc((size_t)512 * 1024 * 2);
    float* bias_hlg = (float*)alloc((size_t)1536 * 4);
    u16* pbf   = (u16*)alloc((size_t)B * 32768 * 2);

    const size_t fixed_used = (size_t)(wsp - (char*)d_ws);
    const size_t perB = 1903104;
    int BC = B;
    while (BC > 1 && fixed_used + (size_t)BC * perB + 4096 > ws_size) BC >>= 1;

    u16* upout = (u16*)alloc((size_t)BC * 131072 * 2);
    u16* gT    = (u16*)alloc((size_t)BC * 262144 * 2);
    u16* xb    = (u16*)alloc((size_t)BC * 262144 * 2);
    u16* hb    = (u16*)alloc((size_t)BC * 65536 * 2);
    u16* lb    = (u16*)alloc((size_t)BC * 65536 * 2);
    u16* atb   = (u16*)alloc((size_t)BC * 65536 * 2);
    u16* p1bf  = (u16*)alloc((size_t)BC * 65536 * 2);
    u16* pdbf  = (u16*)alloc((size_t)BC * 32768 * 2);

    const dim3 tb(64, 4);
    // ---- startup (once) ----
    {
        int n4 = B * 8192;
        int nb = (n4 + 255) / 256; if (nb > 2048) nb = 2048;
        cvt_k<<<dim3(nb), dim3(256), 0, stream>>>(p, pbf, n4);
        transpose_k<true><<<dim3(8, 8, 1),  tb, 0, stream>>>(W_up, WupT, 512, 512);
        transpose_k<true><<<dim3(4, 16, 1), tb, 0, stream>>>(Wh, WhlgT, 1024, 256);
        transpose_k<true><<<dim3(4, 16, 1), tb, 0, stream>>>(Wl, WhlgT + (size_t)256 * 1024, 1024, 256);
        transpose_k<true><<<dim3(16, 16, 1),tb, 0, stream>>>(Wg, WhlgT + (size_t)512 * 1024, 1024, 1024);
        transpose_k<true><<<dim3(8, 16, 1), tb, 0, stream>>>(Wf1, Wf1T, 1024, 512);
        transpose_k<true><<<dim3(4, 8, 1),  tb, 0, stream>>>(Wf2, Wf2T, 512, 256);
        transpose_k<true><<<dim3(8, 16, 1), tb, 0, stream>>>(W_down, WdT, 1024, 512);
        concat3_k<<<dim3(3), dim3(512), 0, stream>>>(bh, bl, bg_, bias_hlg);
    }

    auto run_up = [&](const u16* pin_bf, const float* pin_f32, const u16* pin_ebf,
                      float* f2outF, u16* f2outB, const float* f2EXf, int bc) {
        sp<<<dim3(2, 1, bc / 2), dim3(512), 0, stream>>>(
            pin_bf, WupT, b_up, W_up, upout, 512);
        bp<1><<<dim3(6, bc), dim3(512), 0, stream>>>(
            pin_bf, upout, WhlgT, bias_hlg, nullptr, nullptr, hb, lb, gT, 1024, 0);
        msm<<<dim3(1, 2, bc), dim3(256), 0, stream>>>(lb, hb, atb);
        bp<3><<<dim3(4, bc), dim3(512), 0, stream>>>(
            atb, upout, gT, nullptr, pin_f32, pin_ebf, xb, nullptr, nullptr, 256, 262144);
        bp<4><<<dim3(2, bc), dim3(512), 0, stream>>>(
            xb, nullptr, Wf1T, bf1, nullptr, nullptr, upout, nullptr, nullptr, 1024, 0);
        mg<5><<<dim3(2, 2, bc), dim3(256), 0, stream>>>(
            upout, Wf2T, bf2v, f2EXf, f2outF, f2outB, 512, 0);
    };

    for (int b0 = 0; b0 < B; b0 += BC) {
        const int bc = (B - b0 < BC) ? (B - b0) : BC;
        const u16*   pin_bf  = pbf + (size_t)b0 * 32768;
        const float* pin_f32 = p   + (size_t)b0 * 32768;
        float* outc = out + (size_t)b0 * 65536;
        run_up(pin_bf, pin_f32, nullptr, outc, p1bf, nullptr, bc);
        mg<6><<<dim3(4, 1, bc), dim3(256), 0, stream>>>(
            p1bf, WdT, b_down, pin_f32, nullptr, pdbf, 1024, 0);
        run_up(pdbf, nullptr, pdbf, outc, nullptr, outc, bc);
    }
}